// Round 9
// baseline (130.571 us; speedup 1.0000x reference)
//
#include <hip/hip_runtime.h>
#include <math.h>

#define N_G 512
#define IMG_H 324
#define IMG_W 332
#define N_C 120
#define HW (IMG_H*IMG_W)
#define CHUNK 64
#define PIT 72                 // bf16 row pitch (144 B = 9*16 -> fragments 16B-aligned)
#define TSX 21                 // tiles in x (16 px)
#define TSY 81                 // tiles in y (4 px)
#define NT (TSX*TSY)
#define NBLK 512               // 2 persistent blocks per CU (LDS-capped)

typedef __bf16 bf16x8 __attribute__((ext_vector_type(8)));
typedef float  f32x4  __attribute__((ext_vector_type(4)));

__device__ __forceinline__ unsigned pk2(float a, float b) {
  __bf16 x = (__bf16)a, y = (__bf16)b;
  unsigned short ux = __builtin_bit_cast(unsigned short, x);
  unsigned short uy = __builtin_bit_cast(unsigned short, y);
  return (unsigned)ux | ((unsigned)uy << 16);
}

// ws layout (depth-sorted by k_prep):
//   bb  : [512] float4 {xmin,xmax,ymin,ymax}  cull bbox (6-sigma; empty if skip)
//   ps  : [512][8] {sx, sy, c00s, c11s, log2op, depth, (src*120)_bits, 0}
//   cnt : tile-queue counter (zeroed each launch)
__global__ __launch_bounds__(512) void k_prep(
    const float* __restrict__ pos, const float* __restrict__ scales,
    const float* __restrict__ opac, const float* __restrict__ K,
    const float* __restrict__ E,
    float4* __restrict__ bb, float* __restrict__ ps, int* __restrict__ cnt)
{
  __shared__ float key[N_G];
  const int i = threadIdx.x;
  if (i == 0) *cnt = 0;

  float p0 = pos[i*3+0], p1 = pos[i*3+1], p2 = pos[i*3+2];
  float cam0 = E[0]*p0 + E[1]*p1 + E[2]*p2  + E[3];
  float cam1 = E[4]*p0 + E[5]*p1 + E[6]*p2  + E[7];
  float cam2 = E[8]*p0 + E[9]*p1 + E[10]*p2 + E[11];
  float pr0 = K[0]*cam0 + K[1]*cam1 + K[2]*cam2;
  float pr1 = K[3]*cam0 + K[4]*cam1 + K[5]*cam2;
  float pr2 = K[6]*cam0 + K[7]*cam1 + K[8]*cam2;
  float inv = 1.0f/(pr2 + 1e-6f);
  float sx = pr0*inv, sy = pr1*inv;
  float depth = cam2;

  bool valid = (depth > 0.01f) && (depth < 100.0f)
            && (sx > -100.0f) && (sx < (float)IMG_W + 100.0f)
            && (sy > -100.0f) && (sy < (float)IMG_H + 100.0f);
  bool off = (sx < -(float)IMG_W) || (sx > 2.0f*(float)IMG_W)
          || (sy < -(float)IMG_H) || (sy > 2.0f*(float)IMG_H);
  bool skip = off || (!valid);

  float s0 = scales[i*3+0], s1 = scales[i*3+1];
  float v0 = s0*s0 + 1e-4f, v1 = s1*s1 + 1e-4f;
  const float HL2E = 0.72134752f;              // 0.5*log2(e)
  float c00s = HL2E/v0, c11s = HL2E/v1;
  float op = skip ? 0.0f : opac[i];
  float l2op = __log2f(op);                    // op=0 -> -inf -> exp2 -> 0
  float rx = 6.0f*sqrtf(v0);                   // mahal cutoff 36 (6 sigma)
  float ry = 6.0f*sqrtf(v1);
  float xmin = skip ?  1e9f : sx - rx;
  float xmax = skip ? -1e9f : sx + rx;
  float ymin = skip ?  1e9f : sy - ry;
  float ymax = skip ? -1e9f : sy + ry;

  key[i] = depth;
  __syncthreads();

  int rank = 0;
  #pragma unroll 4
  for (int j = 0; j < N_G; j += 4) {
    float4 k4 = *(const float4*)&key[j];
    rank += (k4.x < depth || (k4.x == depth && j+0 < i)) ? 1 : 0;
    rank += (k4.y < depth || (k4.y == depth && j+1 < i)) ? 1 : 0;
    rank += (k4.z < depth || (k4.z == depth && j+2 < i)) ? 1 : 0;
    rank += (k4.w < depth || (k4.w == depth && j+3 < i)) ? 1 : 0;
  }

  bb[rank] = make_float4(xmin, xmax, ymin, ymax);
  *(float4*)&ps[rank*8]   = make_float4(sx, sy, c00s, c11s);
  *(float4*)&ps[rank*8+4] = make_float4(l2op, depth, __int_as_float(i*N_C), 0.0f);
}

// Persistent blocks pull 16x4-px tiles center-out.
// Per tile, chunks of 64 hits:
//   1a: araw[j][px] (fp32, buf) + stage spec rows -> At[c][k] bf16 (transposed)
//   1b: wave0 per-pixel cumprod -> w; pack bf16 pairs -> Bt[px][k]
//   2 : MFMA GEMM D[c][px] += At(128 x k) * Bt(k x 64), fp32 acc in VGPRs
// Epilogue: D-layout store (+BG*T, *tm); wave0 stores depth & A_final.
#define MFMA(a,b,c) __builtin_amdgcn_mfma_f32_16x16x32_bf16((a),(b),(c),0,0,0)

__global__ __launch_bounds__(256, 2) void k_render(
    const float4* __restrict__ bb, const float* __restrict__ ps,
    int* __restrict__ cnt, const float* __restrict__ spec,
    const float* __restrict__ tm, float* __restrict__ out)
{
  __shared__ float  prm[N_G*8];        // compacted hit params (16 KB)
  __shared__ float  buf[CHUNK*64];     // araw fp32 (16 KB)
  __shared__ __bf16 At[128*PIT];       // spec^T  [chan][k]  (18 KB)
  __shared__ __bf16 Bt[64*PIT];        // w^T     [px][k]    (9 KB)
  __shared__ float  tmL[128];
  __shared__ float  Tcar[64];
  __shared__ int    wcnt[4];
  __shared__ int    stile;

  const int tid  = threadIdx.x;
  const int w    = tid >> 6;
  const int lane = tid & 63;
  const int cl   = lane & 15;          // lane&15: pixel-x / channel-in-tile
  const int quad = lane >> 4;
  const unsigned long long ltm = (1ull << lane) - 1ull;
  const int mc0 = w*32, mc1 = w*32 + 16;   // this wave's channel tiles

  if (tid < N_C) tmL[tid] = tm[tid];
  else if (tid < 128) tmL[tid] = 0.0f;

  for (;;) {
    if (tid == 0) stile = atomicAdd(cnt, 1);
    __syncthreads();
    const int t = stile;
    if (t >= NT) break;
    // center-out bijection: hot center tiles first
    const int jx = t % TSX, ky = t / TSX;
    const int bx = 10 + ((jx & 1) ? ((jx+1)>>1) : -((jx+1)>>1));
    const int by = 40 + ((ky & 1) ? ((ky+1)>>1) : -((ky+1)>>1));

    const int x = bx*16 + cl;
    const int y = by*4 + quad;
    const float px = (float)min(x, IMG_W-1);
    const float py = (float)min(y, IMG_H-1);
    const float wxmin = (float)(bx*16), wxmax = wxmin + 15.0f;
    const float wymin = (float)(by*4),  wymax = wymin + 3.0f;

    // ---- build: 4-wave two-pass ballot compaction (order-preserving) ----
    const int g0 = w*128 + lane;
    const int g1 = g0 + 64;
    float4 b0 = bb[g0], b1 = bb[g1];
    bool h0 = !(b0.x > wxmax || b0.y < wxmin || b0.z > wymax || b0.w < wymin);
    bool h1 = !(b1.x > wxmax || b1.y < wxmin || b1.z > wymax || b1.w < wymin);
    unsigned long long m0 = __ballot(h0), m1 = __ballot(h1);
    int c0 = __popcll(m0), c1 = __popcll(m1);
    if (lane == 0) wcnt[w] = c0 + c1;
    __syncthreads();
    int offw = 0;
    #pragma unroll
    for (int k = 0; k < 4; ++k) if (k < w) offw += wcnt[k];
    const int nh = wcnt[0] + wcnt[1] + wcnt[2] + wcnt[3];
    if (h0) {
      int p = offw + __popcll(m0 & ltm);
      *(float4*)&prm[p*8]   = *(const float4*)&ps[g0*8];
      *(float4*)&prm[p*8+4] = *(const float4*)&ps[g0*8+4];
    }
    if (h1) {
      int p = offw + c0 + __popcll(m1 & ltm);
      *(float4*)&prm[p*8]   = *(const float4*)&ps[g1*8];
      *(float4*)&prm[p*8+4] = *(const float4*)&ps[g1*8+4];
    }
    __syncthreads();

    float T = 1.0f, dacc = 0.0f;       // wave 0 only (lane = pixel)
    f32x4 a00={0,0,0,0}, a01={0,0,0,0}, a02={0,0,0,0}, a03={0,0,0,0};
    f32x4 a10={0,0,0,0}, a11={0,0,0,0}, a12={0,0,0,0}, a13={0,0,0,0};

    for (int cb = 0; cb < nh; cb += CHUNK) {
      const int nc = min(CHUNK, nh - cb);
      const int kpad = (nc + 31) & ~31;
      const int npairs = kpad >> 1;

      // ---- 1a: araw (fp32) + bf16 spec staging (zero-padded K-tail) ----
      for (int tp = w; tp < npairs; tp += 4) {
        const int j0 = 2*tp, j1 = j0 + 1;
        float s00=0.f, s01=0.f, s10=0.f, s11=0.f;
        if (j0 < nc) {
          float4 p0 = *(const float4*)&prm[(cb+j0)*8];
          float4 p1 = *(const float4*)&prm[(cb+j0)*8+4];
          float dx = px - p0.x, dy = py - p0.y;
          buf[j0*64 + lane] = exp2f(p1.x - (p0.z*dx*dx + p0.w*dy*dy));
          int sb = __float_as_int(p1.z);
          s00 = spec[sb + lane];
          if (lane < N_C - 64) s01 = spec[sb + 64 + lane];
        }
        if (j1 < nc) {
          float4 p0 = *(const float4*)&prm[(cb+j1)*8];
          float4 p1 = *(const float4*)&prm[(cb+j1)*8+4];
          float dx = px - p0.x, dy = py - p0.y;
          buf[j1*64 + lane] = exp2f(p1.x - (p0.z*dx*dx + p0.w*dy*dy));
          int sb = __float_as_int(p1.z);
          s10 = spec[sb + lane];
          if (lane < N_C - 64) s11 = spec[sb + 64 + lane];
        }
        *(unsigned*)&At[lane*PIT + j0]      = pk2(s00, s10);
        *(unsigned*)&At[(64+lane)*PIT + j0] = pk2(s01, s11);
      }
      __syncthreads();

      // ---- 1b: per-pixel cumprod (wave 0), pack w -> Bt bf16 ----
      if (w == 0) {
        float wv0 = 0.0f;
        for (int j = 0; j < kpad; ++j) {
          float a = (j < nc) ? buf[j*64 + lane] : 0.0f;
          float wv = a * T;
          T -= wv;
          if (j < nc) dacc = fmaf(prm[(cb+j)*8+5], wv, dacc);
          if (j & 1) *(unsigned*)&Bt[lane*PIT + (j-1)] = pk2(wv0, wv);
          else wv0 = wv;
        }
      }
      __syncthreads();

      // ---- 2: MFMA GEMM  D[c][px] += spec^T * w ----
      const int ksteps = kpad >> 5;
      for (int ks = 0; ks < ksteps; ++ks) {
        const int koff = ks*32 + quad*8;
        bf16x8 A0 = *(const bf16x8*)&At[(mc0 + cl)*PIT + koff];
        bf16x8 A1 = *(const bf16x8*)&At[(mc1 + cl)*PIT + koff];
        bf16x8 B0 = *(const bf16x8*)&Bt[(     cl)*PIT + koff];
        bf16x8 B1 = *(const bf16x8*)&Bt[(16 + cl)*PIT + koff];
        bf16x8 B2 = *(const bf16x8*)&Bt[(32 + cl)*PIT + koff];
        bf16x8 B3 = *(const bf16x8*)&Bt[(48 + cl)*PIT + koff];
        a00 = MFMA(A0, B0, a00);  a01 = MFMA(A0, B1, a01);
        a02 = MFMA(A0, B2, a02);  a03 = MFMA(A0, B3, a03);
        a10 = MFMA(A1, B0, a10);  a11 = MFMA(A1, B1, a11);
        a12 = MFMA(A1, B2, a12);  a13 = MFMA(A1, B3, a13);
      }
      __syncthreads();   // At/Bt/buf reused next chunk
    }

    if (w == 0) Tcar[lane] = T;
    __syncthreads();

    // ---- epilogue: D layout = {chan = mc + quad*4 + r, px = nt*16 + cl} ----
    const bool okx = (x < IMG_W);
    #define ST_TILE(accv, mcb, nt) { \
      float Tf = Tcar[(nt)*16 + cl]; \
      int pixi = (by*4 + (nt))*IMG_W + x; \
      int cc = (mcb) + quad*4; \
      if (okx) { \
        if (cc+0 < N_C) out[(cc+0)*HW + pixi] = (accv.x + Tf)*tmL[cc+0]; \
        if (cc+1 < N_C) out[(cc+1)*HW + pixi] = (accv.y + Tf)*tmL[cc+1]; \
        if (cc+2 < N_C) out[(cc+2)*HW + pixi] = (accv.z + Tf)*tmL[cc+2]; \
        if (cc+3 < N_C) out[(cc+3)*HW + pixi] = (accv.w + Tf)*tmL[cc+3]; \
      } }
    ST_TILE(a00, mc0, 0) ST_TILE(a01, mc0, 1) ST_TILE(a02, mc0, 2) ST_TILE(a03, mc0, 3)
    ST_TILE(a10, mc1, 0) ST_TILE(a11, mc1, 1) ST_TILE(a12, mc1, 2) ST_TILE(a13, mc1, 3)
    #undef ST_TILE

    if (w == 0 && okx) {
      int pixi = y*IMG_W + x;                    // lane = pixel (quad = y-row)
      out[N_C*HW + pixi] = dacc;                 // depth image
      out[N_C*HW + HW + pixi] = 1.0f - T;        // A_final
    }
    __syncthreads();   // protect LDS before next tile
  }
}

extern "C" void kernel_launch(void* const* d_in, const int* in_sizes, int n_in,
                              void* d_out, int out_size, void* d_ws, size_t ws_size,
                              hipStream_t stream) {
  const float* pos    = (const float*)d_in[0];
  // d_in[1] rotations: unused by the reference
  const float* scales = (const float*)d_in[2];
  const float* opac   = (const float*)d_in[3];
  const float* spec   = (const float*)d_in[4];
  const float* tm     = (const float*)d_in[5];
  const float* K      = (const float*)d_in[6];
  const float* E      = (const float*)d_in[7];
  float* out = (float*)d_out;

  float4* bb = (float4*)d_ws;
  float*  ps = (float*)(bb + N_G);
  int*    cnt = (int*)((char*)d_ws + N_G*16 + N_G*32);

  k_prep<<<1, 512, 0, stream>>>(pos, scales, opac, K, E, bb, ps, cnt);
  k_render<<<NBLK, 256, 0, stream>>>(bb, ps, cnt, spec, tm, out);
}